// Round 2
// baseline (3490.799 us; speedup 1.0000x reference)
//
#include <hip/hip_runtime.h>
#include <math.h>

// ---------------- problem constants ----------------
#define NPATH 19
static constexpr int IRD[9]   = {1,3,3,5,5,7,7,9,9};            // 2l+1 per feat irrep
static constexpr int ICUM[9]  = {0,1,4,7,12,17,24,31,40};       // cumulative dims (sum 49)
static constexpr int P_I[NPATH]   = {0,0,0,1,1,1,1,2,2,3,3,4,4,4,4,5,5,6,8};
static constexpr int P_J[NPATH]   = {0,1,2,0,1,1,2,1,2,1,2,0,1,2,2,1,2,2,2};
static constexpr int P_K[NPATH]   = {0,1,2,1,0,2,1,1,2,2,1,2,1,0,2,2,1,2,2};
static constexpr int P_MJ[NPATH]  = {3,2,1,3,2,2,1,2,1,2,1,3,2,1,1,2,1,1,1};
static constexpr int P_MK[NPATH]  = {3,2,1,2,3,1,2,2,1,1,2,1,2,3,1,1,2,1,1};
static constexpr int P_LI[NPATH]  = {0,0,0,1,1,1,1,1,1,2,2,2,2,2,2,3,3,3,4};
static constexpr int P_WOFF[NPATH]= {0,288,416,448,640,832,896,960,1088,1120,1184,1248,1344,1472,1568,1600,1664,1728,1760};
static constexpr int P_BOFF[NPATH]= {0,9,13,0,0,0,0,0,0,0,0,0,0,0,0,0,0,0,0};
static constexpr int P_W3OFF[NPATH]={0,1,10,35,44,53,98,143,170,245,320,395,420,465,490,615,720,825,1000};
static constexpr int ROWOFF[3] = {0,3,9};
#define W3J_TOT 1225

__device__ __forceinline__ float silu_f(float x){ return x / (1.f + expf(-x)); }

// ---------------- Wigner-3j on device (double, e3nn real basis) ----------------
__device__ double dfact(int n){ double r=1.0; for(int i=2;i<=n;i++) r*= (double)i; return r; }

__device__ double su2_cg_d(int j1,int m1,int j2,int m2,int j3,int m3){
  int vmin = max(max(-j1+j2+m3, -j1+m1), 0);
  int vmax = min(min(j2+j3+m1, j3-j1+j2), j3+m3);
  double c = sqrt((double)(2*j3+1)*dfact(j3+j1-j2)*dfact(j3-j1+j2)*dfact(j1+j2-j3)*dfact(j3+m3)*dfact(j3-m3)
     /(dfact(j1+j2+j3+1)*dfact(j1-m1)*dfact(j1+m1)*dfact(j2-m2)*dfact(j2+m2)));
  double s = 0.0;
  for (int v=vmin; v<=vmax; v++){
    double sg = ((v+j2+m2)&1)? -1.0 : 1.0;
    s += sg*dfact(j2+j3+m1-v)*dfact(j1-m1+v)/(dfact(v)*dfact(j3-j1+j2-v)*dfact(j3+m3-v)*dfact(v+j1-j2-m3));
  }
  return c*s;
}

// q[l](row=l+m, col) entry, including (-i)^l factor. Returns complex (x=re,y=im).
__device__ double2 qval(int l, int r, int c){
  int m = r - l;
  const double r2 = 0.70710678118654752440;
  double re=0.0, im=0.0;
  if (m < 0){
    if (c == l - m) re = r2;          // l+|m|
    else if (c == l + m) im = -r2;    // l-|m|
  } else if (m == 0){
    if (c == l) re = 1.0;
  } else {
    double s = (m&1)? -1.0 : 1.0;
    if (c == l + m) re = s*r2;
    else if (c == l - m) im = s*r2;
  }
  switch (l & 3){ // multiply by (-i)^l
    case 0: return make_double2(re, im);
    case 1: return make_double2(im, -re);
    case 2: return make_double2(-re, -im);
    default: return make_double2(-im, re);
  }
}

__global__ void w3j_init_kernel(float* __restrict__ w3){
  int t = blockIdx.x*blockDim.x + threadIdx.x;
  if (t >= W3J_TOT) return;
  int p = 0;
  for (int q=0; q<NPATH; q++) if (t >= P_W3OFF[q]) p = q;
  int l1 = P_J[p], l2 = P_K[p], l3 = P_LI[p];
  int n2=2*l2+1, n3=2*l3+1;
  int loc = t - P_W3OFF[p];
  int m = loc % n3; int jl = loc / n3; int L = jl % n2; int j = jl / n2;
  double inv = 1.0/sqrt((double)n3);
  double accr = 0.0;
  for (int i=0;i<2*l1+1;i++){
    double2 q1 = qval(l1,i,j); if (q1.x==0.0 && q1.y==0.0) continue;
    for (int k=0;k<n2;k++){
      double2 q2 = qval(l2,k,L); if (q2.x==0.0 && q2.y==0.0) continue;
      int m1 = i - l1, m2 = k - l2; int m3 = m1+m2;
      if (m3 < -l3 || m3 > l3) continue;
      double2 q3 = qval(l3,l3+m3,m); if (q3.x==0.0 && q3.y==0.0) continue;
      double cg = su2_cg_d(l1,m1,l2,m2,l3,m3);
      if (cg == 0.0) continue;
      double ar = q1.x*q2.x - q1.y*q2.y;
      double ai = q1.x*q2.y + q1.y*q2.x;
      double br = ar*q3.x + ai*q3.y;   // * conj(q3), real part path
      accr += br*cg;
    }
  }
  w3[t] = (float)(accr * inv);
}

// ---------------- node precompute ----------------
__global__ __launch_bounds__(256) void node_kernel(
  const float* __restrict__ ne,
  const float* __restrict__ W1ii, const float* __restrict__ b1ii,
  const float* __restrict__ W2ii, const float* __restrict__ b2ii,
  const float* __restrict__ W1bii, const float* __restrict__ b1bii,
  const float* __restrict__ W2bii, const float* __restrict__ b2bii,
  const float* __restrict__ W1ij, const float* __restrict__ W1bij,
  float* __restrict__ Afc, float* __restrict__ Bfc,
  float* __restrict__ Afb, float* __restrict__ Bfb,
  float* __restrict__ Wiw, float* __restrict__ Wib)
{
  int n = blockIdx.x, t = threadIdx.x;
  __shared__ float nel[128], hii[128], hbi[128];
  if (t < 128) nel[t] = ne[(size_t)n*128 + t];
  __syncthreads();
  int c = t & 127;
  bool hi = t >= 128;
  {
    const float* Wm = hi ? W1bii : W1ii;
    float a = hi ? b1bii[c] : b1ii[c];
    for (int j=0;j<128;j++) a += nel[j]*Wm[j*128+c];
    float sv = silu_f(a);
    if (hi) hbi[c]=sv; else hii[c]=sv;
  }
  {
    const float* base = W1ij + (hi ? 128*128 : 0);
    float a=0.f; for (int j=0;j<128;j++) a += nel[j]*base[j*128+c];
    (hi?Bfc:Afc)[(size_t)n*128+c] = a;
  }
  {
    const float* base = W1bij + (hi ? 128*128 : 0);
    float a=0.f; for (int j=0;j<128;j++) a += nel[j]*base[j*128+c];
    (hi?Bfb:Afb)[(size_t)n*128+c] = a;
  }
  __syncthreads();
  for (int o=t; o<1792; o+=256){
    float a = b2ii[o];
    for (int cc=0;cc<128;cc++) a += hii[cc]*W2ii[cc*1792+o];
    Wiw[(size_t)n*1792+o]=a;
  }
  if (t < 14){
    float a = b2bii[t];
    for (int cc=0;cc<128;cc++) a += hbi[cc]*W2bii[cc*14+t];
    Wib[(size_t)n*14+t]=a;
  }
}

// ---------------- per-edge hidden (chunked): H[nc,128], Bs[nc,14] ----------------
__global__ __launch_bounds__(256) void edge_hidden_kernel(
  int e0, int nc, const int* __restrict__ ei, int E,
  const float* __restrict__ Afc, const float* __restrict__ Bfc,
  const float* __restrict__ Afb, const float* __restrict__ Bfb,
  const float* __restrict__ b1fc, const float* __restrict__ b1fb,
  const float* __restrict__ W2b, const float* __restrict__ b2b,
  float* __restrict__ H, float* __restrict__ Bs)
{
  int wid = threadIdx.x >> 6, lane = threadIdx.x & 63;
  int el = blockIdx.x*4 + wid;
  if (el >= nc) return;
  int e = e0 + el;
  int s = ei[e], d = ei[E+e];
  const float* As_ = Afc + (size_t)s*128; const float* Bd = Bfc + (size_t)d*128;
  float x0 = As_[lane]+Bd[lane]+b1fc[lane];
  float x1 = As_[lane+64]+Bd[lane+64]+b1fc[lane+64];
  H[(size_t)el*128+lane]    = silu_f(x0);
  H[(size_t)el*128+lane+64] = silu_f(x1);
  const float* Ab = Afb + (size_t)s*128; const float* Bb = Bfb + (size_t)d*128;
  float y0 = Ab[lane]+Bb[lane]+b1fb[lane];
  float y1 = Ab[lane+64]+Bb[lane+64]+b1fb[lane+64];
  float g0 = silu_f(y0), g1 = silu_f(y1);
  float acc[14];
  #pragma unroll
  for (int k=0;k<14;k++) acc[k] = g0*W2b[lane*14+k] + g1*W2b[(lane+64)*14+k];
  #pragma unroll
  for (int k=0;k<14;k++){
    for (int off=32; off>=1; off>>=1) acc[k] += __shfl_xor(acc[k], off, 64);
  }
  if (lane == 0){
    #pragma unroll
    for (int k=0;k<14;k++) Bs[(size_t)el*14+k] = acc[k] + b2b[k];
  }
}

// ---------------- weights GEMM: C[M,1792] = A[M,128] @ Bw[128,1792] + bias ----------------
__global__ __launch_bounds__(256) void wgemm_kernel(
  int M, const float* __restrict__ A, const float* __restrict__ Bw,
  const float* __restrict__ bias, float* __restrict__ C)
{
  __shared__ float As[64][132];  // [row][k], padded
  __shared__ float Bsh[64][64];  // [k-half][col]
  int m0 = blockIdx.x*64, n0 = blockIdx.y*64;
  int t = threadIdx.x;
  for (int idx=t; idx<2048; idx+=256){
    int row = idx>>5, kq = idx&31;
    float4 v = make_float4(0.f,0.f,0.f,0.f);
    if (m0+row < M) v = *(const float4*)&A[(size_t)(m0+row)*128 + 4*kq];
    *(float4*)&As[row][4*kq] = v;
  }
  int ty = t>>4, tx = t&15;
  float acc[4][4] = {};
  for (int kh=0; kh<2; kh++){
    __syncthreads();
    for (int idx=t; idx<1024; idx+=256){
      int kk = idx>>4, cq = idx&15;
      *(float4*)&Bsh[kk][4*cq] = *(const float4*)&Bw[(size_t)(kh*64+kk)*1792 + n0 + 4*cq];
    }
    __syncthreads();
    for (int k=0;k<64;k++){
      int kk = kh*64+k;
      float a0=As[ty*4+0][kk], a1=As[ty*4+1][kk], a2=As[ty*4+2][kk], a3=As[ty*4+3][kk];
      float4 b4 = *(const float4*)&Bsh[k][tx*4];
      acc[0][0]+=a0*b4.x; acc[0][1]+=a0*b4.y; acc[0][2]+=a0*b4.z; acc[0][3]+=a0*b4.w;
      acc[1][0]+=a1*b4.x; acc[1][1]+=a1*b4.y; acc[1][2]+=a1*b4.z; acc[1][3]+=a1*b4.w;
      acc[2][0]+=a2*b4.x; acc[2][1]+=a2*b4.y; acc[2][2]+=a2*b4.z; acc[2][3]+=a2*b4.w;
      acc[3][0]+=a3*b4.x; acc[3][1]+=a3*b4.y; acc[3][2]+=a3*b4.z; acc[3][3]+=a3*b4.w;
    }
  }
  float4 bb = *(const float4*)&bias[n0 + tx*4];
  #pragma unroll
  for (int i=0;i<4;i++){
    int row = m0 + ty*4 + i;
    if (row < M){
      float4 o;
      o.x = acc[i][0]+bb.x; o.y = acc[i][1]+bb.y; o.z = acc[i][2]+bb.z; o.w = acc[i][3]+bb.w;
      *(float4*)&C[(size_t)row*1792 + n0 + tx*4] = o;
    }
  }
}

// ---------------- fused o3_linear + expansion ----------------
__global__ __launch_bounds__(192) void expansion_kernel(
  int B,
  const float* __restrict__ feat,
  const float* __restrict__ wmat,
  const float* __restrict__ Wt,
  const float* __restrict__ Bsv,
  const float* __restrict__ w3j,
  float* __restrict__ out)
{
  __shared__ __align__(16) float fseg[6*576];   // per-irrep feature tile
  __shared__ float xs[6*1617];                  // [bl][49][33] padded
  __shared__ float outt[6*196];
  const int t = threadIdx.x;
  const int b0 = blockIdx.x*6;
  for (int idx=t; idx<6*196; idx+=192) outt[idx]=0.f;
  const int bl = t>>5, w = t&31;
  const int bb = b0 + bl;

  #pragma unroll
  for (int i=0;i<9;i++){
    const int d = IRD[i], cum = ICUM[i];
    const int segq = 16*d;                      // float4 count per item (64*d/4)
    __syncthreads();
    for (int idx=t; idx<6*segq; idx+=192){
      int sb = idx/segq, q = idx - sb*segq;
      float4 v = make_float4(0.f,0.f,0.f,0.f);
      if (b0+sb < B) v = *(const float4*)(feat + (size_t)(b0+sb)*3136 + 64*cum + 4*q);
      *(float4*)(fseg + sb*576 + 4*q) = v;
    }
    __syncthreads();
    if (bb < B){
      float acc[9];
      #pragma unroll
      for (int k=0;k<d;k++) acc[k]=0.f;
      const float* wp = wmat + i*2048 + w;
      const float* fp = fseg + bl*576;
      for (int u=0;u<64;u++){
        float wv = wp[u*32];
        #pragma unroll
        for (int k=0;k<d;k++) acc[k] += fp[u*d+k]*wv;
      }
      #pragma unroll
      for (int k=0;k<d;k++) xs[bl*1617 + (cum+k)*33 + w] = 0.125f*acc[k];
    }
  }
  __syncthreads();

  #pragma unroll
  for (int p=0;p<NPATH;p++){
    const int mj=P_MJ[p], mk=P_MK[p], mjk=mj*mk;
    const int di = IRD[P_I[p]];
    const int dj = 2*P_J[p]+1, dk = 2*P_K[p]+1;
    const int items = 6*mjk;
    if (t < items){
      const int sb = t/mjk, uv = t - sb*mjk;
      const int u = uv/mk, v = uv - u*mk;
      const int b = b0 + sb;
      if (b < B){
        const float* wrow = Wt + (size_t)b*1792 + P_WOFF[p] + uv;
        const float* xp = xs + sb*1617 + ICUM[P_I[p]]*33;
        float r[9];
        #pragma unroll
        for (int k=0;k<di;k++) r[k]=0.f;
        for (int ww=0; ww<32; ww++){
          float wt = wrow[ww*mjk];
          #pragma unroll
          for (int k=0;k<di;k++) r[k] += wt * xp[k*33 + ww];
        }
        if (P_LI[p]==0) r[0] += Bsv[(size_t)b*14 + P_BOFF[p] + uv];
        const float* C3 = w3j + P_W3OFF[p];
        const int ro = ROWOFF[P_J[p]] + u*dj;
        const int co = ROWOFF[P_K[p]] + v*dk;
        float* op = outt + sb*196;
        #pragma unroll
        for (int a=0;a<dj;a++){
          #pragma unroll
          for (int cc=0;cc<dk;cc++){
            float s2 = 0.f;
            #pragma unroll
            for (int k=0;k<di;k++) s2 += C3[(a*dk+cc)*di + k] * r[k];
            op[(ro+a)*14 + (co+cc)] += s2 * (1.f/32.f);
          }
        }
      }
    }
    __syncthreads();  // (J,K) blocks shared across paths
  }
  for (int idx=t; idx<6*196; idx+=192){
    int sb = idx/196;
    if (b0+sb < B) out[(size_t)(b0+sb)*196 + (idx - sb*196)] = outt[idx];
  }
}

// ---------------- reverse-edge lookup + symmetrization (in-place, pairwise) ----------------
__global__ void pos_init_kernel(int* __restrict__ pos, int n){
  int t = blockIdx.x*blockDim.x + threadIdx.x;
  if (t < n) pos[t] = -1;
}
__global__ void pos_fill_kernel(int* __restrict__ pos, const int* __restrict__ ei, int E, int N){
  int t = blockIdx.x*blockDim.x + threadIdx.x;
  if (t < E) pos[ei[t]*N + ei[E+t]] = t;
}
__global__ void sym_diag_kernel(float* __restrict__ out, int N){
  int t = blockIdx.x*blockDim.x + threadIdx.x;
  if (t >= N*196) return;
  int n = t/196, rc = t - n*196, r = rc/14, c = rc - r*14;
  if (r >= c) return;
  float* M = out + (size_t)n*196;
  float a = M[r*14+c], b = M[c*14+r];
  float v = 0.5f*(a+b);
  M[r*14+c]=v; M[c*14+r]=v;
}
__global__ void sym_off_kernel(float* __restrict__ out, const int* __restrict__ ei,
                               const int* __restrict__ pos, int E, int N){
  long long t = (long long)blockIdx.x*blockDim.x + threadIdx.x;
  if (t >= (long long)E*196) return;
  int e = (int)(t/196); int rc = (int)(t - (long long)e*196);
  int r = rc/14, c = rc - r*14;
  int s = ei[e], d = ei[E+e];
  int e2 = pos[d*N+s];
  if (e2 < 0 || e2 <= e) return;     // partner thread handles the pair once
  float* Me = out + (size_t)e*196;
  float* Mf = out + (size_t)e2*196;
  float a = Me[rc], b = Mf[c*14+r];
  float v = 0.5f*(a+b);
  Me[rc]=v; Mf[c*14+r]=v;
}

static inline long long llmin(long long a, long long b){ return a<b?a:b; }
static inline long long llmax(long long a, long long b){ return a>b?a:b; }

extern "C" void kernel_launch(void* const* d_in, const int* in_sizes, int n_in,
                              void* d_out, int out_size, void* d_ws, size_t ws_size,
                              hipStream_t stream) {
  const float* fii = (const float*)d_in[0];
  const float* fij = (const float*)d_in[1];
  const float* ne  = (const float*)d_in[2];
  const int*   ei  = (const int*)d_in[3];
  const float* wii = (const float*)d_in[4];
  const float* wij = (const float*)d_in[5];
  const float* iifc_w1 = (const float*)d_in[6];
  const float* iifc_b1 = (const float*)d_in[7];
  const float* iifc_w2 = (const float*)d_in[8];
  const float* iifc_b2 = (const float*)d_in[9];
  const float* iifb_w1 = (const float*)d_in[10];
  const float* iifb_b1 = (const float*)d_in[11];
  const float* iifb_w2 = (const float*)d_in[12];
  const float* iifb_b2 = (const float*)d_in[13];
  const float* ijfc_w1 = (const float*)d_in[14];
  const float* ijfc_b1 = (const float*)d_in[15];
  const float* ijfc_w2 = (const float*)d_in[16];
  const float* ijfc_b2 = (const float*)d_in[17];
  const float* ijfb_w1 = (const float*)d_in[18];
  const float* ijfb_b1 = (const float*)d_in[19];
  const float* ijfb_w2 = (const float*)d_in[20];
  const float* ijfb_b2 = (const float*)d_in[21];
  (void)n_in; (void)out_size;
  float* out = (float*)d_out;
  const int N = in_sizes[2]/128;
  const int E = in_sizes[1]/3136;

  float* ws = (float*)d_ws;
  size_t o_Afc = 0;
  size_t o_Bfc = o_Afc + (size_t)N*128;
  size_t o_Afb = o_Bfc + (size_t)N*128;
  size_t o_Bfb = o_Afb + (size_t)N*128;
  size_t o_Wiw = o_Bfb + (size_t)N*128;
  size_t o_Wib = o_Wiw + (size_t)N*1792;
  size_t o_w3j = o_Wib + (size_t)N*14;
  size_t o_pos = o_w3j + 1232;
  size_t o_dyn = o_pos + (size_t)N*N + 16;
  long long avail = (long long)(ws_size/4) - (long long)o_dyn;
  long long per_e = 128 + 14 + 1792;
  long long CHl = avail > 0 ? avail/per_e : 1;   // strict clamp: never exceed ws
  CHl = llmin(CHl, E);
  CHl = llmax(CHl, 1);
  const int CH = (int)CHl;
  size_t o_H  = o_dyn;
  size_t o_Bs = o_H + (size_t)CH*128;
  size_t o_Wt = o_Bs + (size_t)CH*14;
  int* pos = (int*)(ws + o_pos);

  w3j_init_kernel<<<(W3J_TOT+255)/256, 256, 0, stream>>>(ws + o_w3j);
  node_kernel<<<N, 256, 0, stream>>>(ne,
      iifc_w1, iifc_b1, iifc_w2, iifc_b2,
      iifb_w1, iifb_b1, iifb_w2, iifb_b2,
      ijfc_w1, ijfb_w1,
      ws+o_Afc, ws+o_Bfc, ws+o_Afb, ws+o_Bfb, ws+o_Wiw, ws+o_Wib);
  pos_init_kernel<<<(N*N+255)/256, 256, 0, stream>>>(pos, N*N);
  pos_fill_kernel<<<(E+255)/256, 256, 0, stream>>>(pos, ei, E, N);

  // diagonal blocks
  expansion_kernel<<<(N+5)/6, 192, 0, stream>>>(N, fii, wii, ws+o_Wiw, ws+o_Wib, ws+o_w3j, out);

  // off-diagonal blocks, edge-chunked to fit workspace
  for (int e0 = 0; e0 < E; e0 += CH){
    int nc = (E - e0 < CH) ? (E - e0) : CH;
    edge_hidden_kernel<<<(nc+3)/4, 256, 0, stream>>>(e0, nc, ei, E,
        ws+o_Afc, ws+o_Bfc, ws+o_Afb, ws+o_Bfb,
        ijfc_b1, ijfb_b1, ijfb_w2, ijfb_b2,
        ws+o_H, ws+o_Bs);
    wgemm_kernel<<<dim3((nc+63)/64, 28), 256, 0, stream>>>(nc, ws+o_H, ijfc_w2, ijfc_b2, ws+o_Wt);
    expansion_kernel<<<(nc+5)/6, 192, 0, stream>>>(nc, fij + (size_t)e0*3136, wij,
        ws+o_Wt, ws+o_Bs, ws+o_w3j, out + ((size_t)N + e0)*196);
  }

  sym_diag_kernel<<<(N*196+255)/256, 256, 0, stream>>>(out, N);
  sym_off_kernel<<<(int)(((long long)E*196 + 255)/256), 256, 0, stream>>>(out + (size_t)N*196, ei, pos, E, N);
}

// Round 3
// 1211.457 us; speedup vs baseline: 2.8815x; 2.8815x over previous
//
#include <hip/hip_runtime.h>
#include <math.h>

// ---------------- problem constants ----------------
#define NPATH 19
static constexpr int IRD[9]   = {1,3,3,5,5,7,7,9,9};            // 2l+1 per feat irrep
static constexpr int ICUM[9]  = {0,1,4,7,12,17,24,31,40};       // cumulative dims (sum 49)
static constexpr int P_I[NPATH]   = {0,0,0,1,1,1,1,2,2,3,3,4,4,4,4,5,5,6,8};
static constexpr int P_J[NPATH]   = {0,1,2,0,1,1,2,1,2,1,2,0,1,2,2,1,2,2,2};
static constexpr int P_K[NPATH]   = {0,1,2,1,0,2,1,1,2,2,1,2,1,0,2,2,1,2,2};
static constexpr int P_MJ[NPATH]  = {3,2,1,3,2,2,1,2,1,2,1,3,2,1,1,2,1,1,1};
static constexpr int P_MK[NPATH]  = {3,2,1,2,3,1,2,2,1,1,2,1,2,3,1,1,2,1,1};
static constexpr int P_WOFF[NPATH]= {0,288,416,448,640,832,896,960,1088,1120,1184,1248,1344,1472,1568,1600,1664,1728,1760};
static constexpr int P_W3OFF[NPATH]={0,1,10,35,44,53,98,143,170,245,320,395,420,465,490,615,720,825,1000};
// component prefix (mjk*di) and weight-row prefix (mjk)
static constexpr int CB_[NPATH] = {0,9,13,14,32,50,56,62,74,77,87,97,112,132,147,152,166,180,187}; // total 196
static constexpr int WB_[NPATH] = {0,9,13,14,20,26,28,30,34,35,37,39,42,46,49,50,52,54,55};        // total 56
#define W3J_TOT 1225
#define NCOMP 196
#define NWROW 56
#define MAXNNZ 4096

__device__ __forceinline__ float silu_f(float x){ return x / (1.f + expf(-x)); }

// ---------------- Wigner-3j helpers (double, e3nn real basis) ----------------
__device__ double dfact(int n){ double r=1.0; for(int i=2;i<=n;i++) r*= (double)i; return r; }

__device__ double su2_cg_d(int j1,int m1,int j2,int m2,int j3,int m3){
  int vmin = max(max(-j1+j2+m3, -j1+m1), 0);
  int vmax = min(min(j2+j3+m1, j3-j1+j2), j3+m3);
  double c = sqrt((double)(2*j3+1)*dfact(j3+j1-j2)*dfact(j3-j1+j2)*dfact(j1+j2-j3)*dfact(j3+m3)*dfact(j3-m3)
     /(dfact(j1+j2+j3+1)*dfact(j1-m1)*dfact(j1+m1)*dfact(j2-m2)*dfact(j2+m2)));
  double s = 0.0;
  for (int v=vmin; v<=vmax; v++){
    double sg = ((v+j2+m2)&1)? -1.0 : 1.0;
    s += sg*dfact(j2+j3+m1-v)*dfact(j1-m1+v)/(dfact(v)*dfact(j3-j1+j2-v)*dfact(j3+m3-v)*dfact(v+j1-j2-m3));
  }
  return c*s;
}

__device__ double2 qval(int l, int r, int c){
  int m = r - l;
  const double r2 = 0.70710678118654752440;
  double re=0.0, im=0.0;
  if (m < 0){
    if (c == l - m) re = r2;
    else if (c == l + m) im = -r2;
  } else if (m == 0){
    if (c == l) re = 1.0;
  } else {
    double s = (m&1)? -1.0 : 1.0;
    if (c == l + m) re = s*r2;
    else if (c == l - m) im = s*r2;
  }
  switch (l & 3){
    case 0: return make_double2(re, im);
    case 1: return make_double2(im, -re);
    case 2: return make_double2(-re, -im);
    default: return make_double2(-im, re);
  }
}

__device__ __forceinline__ void dec_rc(int r, int& j, int& u, int& a){
  if (r < 3){ j=0; u=r; a=0; }
  else if (r < 9){ j=1; u=(r-3)/3; a=(r-3)%3; }
  else { j=2; u=0; a=r-9; }
}

// ---------------- init: w3j + perm + comp tables + CSR (single block) ----------------
__global__ __launch_bounds__(256) void init_kernel(
  float* __restrict__ w3, int* __restrict__ perm,
  int2* __restrict__ comp, int* __restrict__ rst, int* __restrict__ rln,
  int2* __restrict__ ent)
{
  const int t = threadIdx.x;
  // --- w3j values ---
  for (int e = t; e < W3J_TOT; e += 256){
    int p = 0;
    for (int q=0; q<NPATH; q++) if (e >= P_W3OFF[q]) p = q;
    int l1 = P_J[p], l2 = P_K[p], l3 = 0;
    { int li = P_I[p]; l3 = (IRD[li]-1)/2; }
    int n2=2*l2+1, n3=2*l3+1;
    int loc = e - P_W3OFF[p];
    int m = loc % n3; int jl = loc / n3; int L = jl % n2; int j = jl / n2;
    double inv = 1.0/sqrt((double)n3);
    double accr = 0.0;
    for (int i=0;i<2*l1+1;i++){
      double2 q1 = qval(l1,i,j); if (q1.x==0.0 && q1.y==0.0) continue;
      for (int k=0;k<n2;k++){
        double2 q2 = qval(l2,k,L); if (q2.x==0.0 && q2.y==0.0) continue;
        int m1 = i - l1, m2 = k - l2; int m3 = m1+m2;
        if (m3 < -l3 || m3 > l3) continue;
        double2 q3 = qval(l3,l3+m3,m); if (q3.x==0.0 && q3.y==0.0) continue;
        double cg = su2_cg_d(l1,m1,l2,m2,l3,m3);
        if (cg == 0.0) continue;
        double ar = q1.x*q2.x - q1.y*q2.y;
        double ai = q1.x*q2.y + q1.y*q2.x;
        double br = ar*q3.x + ai*q3.y;
        accr += br*cg;
      }
    }
    w3[e] = (float)(accr * inv);
  }
  // --- column permutation old->new for weight layout [(p,uv)][w] ---
  for (int idx = t; idx < 1792; idx += 256){
    int p = 0;
    for (int q=0; q<NPATH; q++) if (idx >= P_WOFF[q]) p = q;
    int mjk = P_MJ[p]*P_MK[p];
    int loc = idx - P_WOFF[p];
    int w = loc / mjk, uv = loc % mjk;
    perm[idx] = (WB_[p]+uv)*32 + w;
  }
  // --- component tables: comp[c] = (x-row, wt-row) ---
  if (t < NCOMP){
    int p = 0;
    for (int q=0; q<NPATH; q++) if (t >= CB_[q]) p = q;
    int di = IRD[P_I[p]];
    int loc = t - CB_[p]; int uv = loc/di, k = loc%di;
    comp[t] = make_int2(ICUM[P_I[p]] + k, WB_[p] + uv);
  }
  __syncthreads();   // w3 ready
  // --- CSR of the [196 out x 196 R] matrix ---
  __shared__ int lens[NCOMP];
  __shared__ int starts[NCOMP+1];
  if (t < NCOMP){
    int r = t/14, c = t%14;
    int j,u,a, k,v,cc;
    dec_rc(r, j,u,a); dec_rc(c, k,v,cc);
    int cnt = 0;
    for (int p=0;p<NPATH;p++){
      if (P_J[p]==j && P_K[p]==k){
        int di = IRD[P_I[p]]; int dk = 2*k+1;
        for (int kk=0; kk<di; kk++){
          float cf = w3[P_W3OFF[p] + (a*dk+cc)*di + kk];
          if (fabsf(cf) > 1e-10f) cnt++;
        }
      }
    }
    lens[t] = cnt;
  }
  __syncthreads();
  if (t == 0){
    int s = 0;
    for (int i=0;i<NCOMP;i++){ starts[i]=s; s+=lens[i]; }
    starts[NCOMP]=s;
  }
  __syncthreads();
  if (t < NCOMP){
    rst[t] = starts[t]; rln[t] = lens[t];
    int r = t/14, c = t%14;
    int j,u,a, k,v,cc;
    dec_rc(r, j,u,a); dec_rc(c, k,v,cc);
    int pp = starts[t];
    for (int p=0;p<NPATH;p++){
      if (P_J[p]==j && P_K[p]==k){
        int di = IRD[P_I[p]]; int dk = 2*k+1; int mk = P_MK[p];
        for (int kk=0; kk<di; kk++){
          float cf = w3[P_W3OFF[p] + (a*dk+cc)*di + kk];
          if (fabsf(cf) > 1e-10f){
            int ridx = CB_[p] + (u*mk+v)*di + kk;
            ent[pp++] = make_int2(ridx, __float_as_int(cf * (1.f/32.f)));
          }
        }
      }
    }
  }
}

// ---------------- permute B columns of the big weight GEMM ----------------
__global__ void permB_kernel(const float* __restrict__ W2, const float* __restrict__ b2,
                             const int* __restrict__ perm,
                             float* __restrict__ Bp, float* __restrict__ bp){
  int idx = blockIdx.x*256 + threadIdx.x;
  if (idx < 128*1792){
    int o = idx % 1792; int k = idx / 1792;
    Bp[(size_t)k*1792 + perm[o]] = W2[idx];
  }
  if (idx < 1792) bp[perm[idx]] = b2[idx];
}

// ---------------- node precompute ----------------
__global__ __launch_bounds__(256) void node_kernel(
  const float* __restrict__ ne,
  const float* __restrict__ W1ii, const float* __restrict__ b1ii,
  const float* __restrict__ W2ii, const float* __restrict__ b2ii,
  const float* __restrict__ W1bii, const float* __restrict__ b1bii,
  const float* __restrict__ W2bii, const float* __restrict__ b2bii,
  const float* __restrict__ W1ij, const float* __restrict__ W1bij,
  const int* __restrict__ perm,
  float* __restrict__ Afc, float* __restrict__ Bfc,
  float* __restrict__ Afb, float* __restrict__ Bfb,
  float* __restrict__ Wiw, float* __restrict__ Wib)
{
  int n = blockIdx.x, t = threadIdx.x;
  __shared__ float nel[128], hii[128], hbi[128];
  if (t < 128) nel[t] = ne[(size_t)n*128 + t];
  __syncthreads();
  int c = t & 127;
  bool hi = t >= 128;
  {
    const float* Wm = hi ? W1bii : W1ii;
    float a = hi ? b1bii[c] : b1ii[c];
    for (int j=0;j<128;j++) a += nel[j]*Wm[j*128+c];
    float sv = silu_f(a);
    if (hi) hbi[c]=sv; else hii[c]=sv;
  }
  {
    const float* base = W1ij + (hi ? 128*128 : 0);
    float a=0.f; for (int j=0;j<128;j++) a += nel[j]*base[j*128+c];
    (hi?Bfc:Afc)[(size_t)n*128+c] = a;
  }
  {
    const float* base = W1bij + (hi ? 128*128 : 0);
    float a=0.f; for (int j=0;j<128;j++) a += nel[j]*base[j*128+c];
    (hi?Bfb:Afb)[(size_t)n*128+c] = a;
  }
  __syncthreads();
  for (int o=t; o<1792; o+=256){
    float a = b2ii[o];
    for (int cc=0;cc<128;cc++) a += hii[cc]*W2ii[cc*1792+o];
    Wiw[(size_t)n*1792 + perm[o]] = a;   // permuted layout
  }
  if (t < 14){
    float a = b2bii[t];
    for (int cc=0;cc<128;cc++) a += hbi[cc]*W2bii[cc*14+t];
    Wib[(size_t)n*14+t]=a;
  }
}

// ---------------- per-edge hidden: H[nc,128], Bs[nc,14] ----------------
__global__ __launch_bounds__(256) void edge_hidden_kernel(
  int e0, int nc, const int* __restrict__ ei, int E,
  const float* __restrict__ Afc, const float* __restrict__ Bfc,
  const float* __restrict__ Afb, const float* __restrict__ Bfb,
  const float* __restrict__ b1fc, const float* __restrict__ b1fb,
  const float* __restrict__ W2b, const float* __restrict__ b2b,
  float* __restrict__ H, float* __restrict__ Bs)
{
  int wid = threadIdx.x >> 6, lane = threadIdx.x & 63;
  int el = blockIdx.x*4 + wid;
  if (el >= nc) return;
  int e = e0 + el;
  int s = ei[e], d = ei[E+e];
  const float* As_ = Afc + (size_t)s*128; const float* Bd = Bfc + (size_t)d*128;
  float x0 = As_[lane]+Bd[lane]+b1fc[lane];
  float x1 = As_[lane+64]+Bd[lane+64]+b1fc[lane+64];
  H[(size_t)el*128+lane]    = silu_f(x0);
  H[(size_t)el*128+lane+64] = silu_f(x1);
  const float* Ab = Afb + (size_t)s*128; const float* Bb = Bfb + (size_t)d*128;
  float y0 = Ab[lane]+Bb[lane]+b1fb[lane];
  float y1 = Ab[lane+64]+Bb[lane+64]+b1fb[lane+64];
  float g0 = silu_f(y0), g1 = silu_f(y1);
  float acc[14];
  #pragma unroll
  for (int k=0;k<14;k++) acc[k] = g0*W2b[lane*14+k] + g1*W2b[(lane+64)*14+k];
  #pragma unroll
  for (int k=0;k<14;k++){
    for (int off=32; off>=1; off>>=1) acc[k] += __shfl_xor(acc[k], off, 64);
  }
  if (lane == 0){
    #pragma unroll
    for (int k=0;k<14;k++) Bs[(size_t)el*14+k] = acc[k] + b2b[k];
  }
}

// ---------------- weights GEMM v2: C[M,1792] = A[M,128]@Bp + bp (permuted cols) ----------------
// tile 128x64, thread 8x4, A transposed in LDS so inner loop is b128-only.
__global__ __launch_bounds__(256) void wgemm2_kernel(
  int M, const float* __restrict__ A, const float* __restrict__ Bp,
  const float* __restrict__ bp, float* __restrict__ C)
{
  __shared__ __align__(16) float As2[64][132];  // [k][row], padded
  __shared__ __align__(16) float Bsh[64][68];   // [k][col], padded
  const int t = threadIdx.x;
  const int m0 = blockIdx.x*128, n0 = blockIdx.y*64;
  const int ty = t >> 4, tx = t & 15;           // rows ty*8.., cols tx*4..
  float acc[8][4] = {};
  for (int kh=0; kh<2; kh++){
    __syncthreads();
    // stage A transposed: 128 rows x 64 k = 2048 float4 over k
    for (int q=t; q<2048; q+=256){
      int row = q >> 4, k4 = q & 15;
      float4 v = make_float4(0.f,0.f,0.f,0.f);
      if (m0+row < M) v = *(const float4*)&A[(size_t)(m0+row)*128 + kh*64 + k4*4];
      As2[k4*4+0][row] = v.x; As2[k4*4+1][row] = v.y;
      As2[k4*4+2][row] = v.z; As2[k4*4+3][row] = v.w;
    }
    // stage B: 64 k x 64 cols
    for (int q=t; q<1024; q+=256){
      int k = q >> 4, c4 = q & 15;
      *(float4*)&Bsh[k][c4*4] = *(const float4*)&Bp[(size_t)(kh*64+k)*1792 + n0 + c4*4];
    }
    __syncthreads();
    #pragma unroll 4
    for (int k=0;k<64;k++){
      float4 a0 = *(const float4*)&As2[k][ty*8];
      float4 a1 = *(const float4*)&As2[k][ty*8+4];
      float4 b4 = *(const float4*)&Bsh[k][tx*4];
      acc[0][0]+=a0.x*b4.x; acc[0][1]+=a0.x*b4.y; acc[0][2]+=a0.x*b4.z; acc[0][3]+=a0.x*b4.w;
      acc[1][0]+=a0.y*b4.x; acc[1][1]+=a0.y*b4.y; acc[1][2]+=a0.y*b4.z; acc[1][3]+=a0.y*b4.w;
      acc[2][0]+=a0.z*b4.x; acc[2][1]+=a0.z*b4.y; acc[2][2]+=a0.z*b4.z; acc[2][3]+=a0.z*b4.w;
      acc[3][0]+=a0.w*b4.x; acc[3][1]+=a0.w*b4.y; acc[3][2]+=a0.w*b4.z; acc[3][3]+=a0.w*b4.w;
      acc[4][0]+=a1.x*b4.x; acc[4][1]+=a1.x*b4.y; acc[4][2]+=a1.x*b4.z; acc[4][3]+=a1.x*b4.w;
      acc[5][0]+=a1.y*b4.x; acc[5][1]+=a1.y*b4.y; acc[5][2]+=a1.y*b4.z; acc[5][3]+=a1.y*b4.w;
      acc[6][0]+=a1.z*b4.x; acc[6][1]+=a1.z*b4.y; acc[6][2]+=a1.z*b4.z; acc[6][3]+=a1.z*b4.w;
      acc[7][0]+=a1.w*b4.x; acc[7][1]+=a1.w*b4.y; acc[7][2]+=a1.w*b4.z; acc[7][3]+=a1.w*b4.w;
    }
  }
  float4 bb = *(const float4*)&bp[n0 + tx*4];
  #pragma unroll
  for (int i=0;i<8;i++){
    int row = m0 + ty*8 + i;
    if (row < M){
      float4 o;
      o.x = acc[i][0]+bb.x; o.y = acc[i][1]+bb.y; o.z = acc[i][2]+bb.z; o.w = acc[i][3]+bb.w;
      *(float4*)&C[(size_t)row*1792 + n0 + tx*4] = o;
    }
  }
}

// ---------------- o3_linear GEMM: X[item][49][32] ----------------
// per irrep: C[(e,m), o] = 0.125 * sum_u F[e, cum*64 + u*di + m] * W[ir][u][o]
__global__ __launch_bounds__(256) void o3lin_kernel(
  int B, const float* __restrict__ F, const float* __restrict__ W, float* __restrict__ X)
{
  const int ir = blockIdx.y;
  const int di = IRD[ir], cum = ICUM[ir];
  const int M = B*di;
  const int r0 = blockIdx.x*128;
  if (r0 >= M) return;
  __shared__ __align__(16) float As2[64][128];  // [u][row]
  __shared__ __align__(16) float Wsh[64*32];    // [u][o]
  const int t = threadIdx.x;
  for (int q=t; q<512; q+=256)
    *(float4*)&Wsh[q*4] = *(const float4*)&W[ir*2048 + q*4];
  {
    int r = t & 127, uh = t >> 7;          // uh in {0,1}
    int row = r0 + r;
    if (row < M){
      int e = row / di, m = row - e*di;
      const float* fb = F + (size_t)e*3136 + cum*64 + m;
      #pragma unroll 8
      for (int i=0;i<32;i++){
        int u = uh*32 + i;
        As2[u][r] = fb[u*di];
      }
    } else {
      #pragma unroll 8
      for (int i=0;i<32;i++) As2[uh*32+i][r] = 0.f;
    }
  }
  __syncthreads();
  const int ty = t >> 3, tx = t & 7;       // rows ty*4.., cols tx*4..
  float acc[4][4] = {};
  #pragma unroll 4
  for (int u=0;u<64;u++){
    float4 a = *(const float4*)&As2[u][ty*4];
    float4 b = *(const float4*)&Wsh[u*32 + tx*4];
    acc[0][0]+=a.x*b.x; acc[0][1]+=a.x*b.y; acc[0][2]+=a.x*b.z; acc[0][3]+=a.x*b.w;
    acc[1][0]+=a.y*b.x; acc[1][1]+=a.y*b.y; acc[1][2]+=a.y*b.z; acc[1][3]+=a.y*b.w;
    acc[2][0]+=a.z*b.x; acc[2][1]+=a.z*b.y; acc[2][2]+=a.z*b.z; acc[2][3]+=a.z*b.w;
    acc[3][0]+=a.w*b.x; acc[3][1]+=a.w*b.y; acc[3][2]+=a.w*b.z; acc[3][3]+=a.w*b.w;
  }
  #pragma unroll
  for (int i=0;i<4;i++){
    int row = r0 + ty*4 + i;
    if (row < M){
      int e = row / di, m = row - e*di;
      float4 o;
      o.x = acc[i][0]*0.125f; o.y = acc[i][1]*0.125f;
      o.z = acc[i][2]*0.125f; o.w = acc[i][3]*0.125f;
      *(float4*)&X[(size_t)e*1568 + (cum+m)*32 + tx*4] = o;
    }
  }
}

// ---------------- expansion v2: R components + CSR apply ----------------
// 2 items per 256-thread block. X rows and Wt rows are 32 floats; staged padded to 36.
__global__ __launch_bounds__(256) void expansion2_kernel(
  int B, const float* __restrict__ X, const float* __restrict__ Wt,
  const float* __restrict__ Bs,
  const int2* __restrict__ comp, const int* __restrict__ rst,
  const int* __restrict__ rln, const int2* __restrict__ ent,
  float* __restrict__ out)
{
  __shared__ __align__(16) float Xs[2][49*36];
  __shared__ __align__(16) float Wsl[2][56*36];
  __shared__ float Rs[2][200];
  __shared__ float Bl[2][14];
  const int t = threadIdx.x;
  const int g0 = blockIdx.x*2;
  for (int g=0; g<2; g++){
    int b = g0+g;
    if (b >= B) break;
    const float4* X4 = (const float4*)(X + (size_t)b*1568);
    for (int q=t; q<392; q+=256){
      float4 v = X4[q];
      int row = q >> 3, w4 = q & 7;
      *(float4*)&Xs[g][row*36 + w4*4] = v;
    }
    const float4* W4 = (const float4*)(Wt + (size_t)b*1792);
    for (int q=t; q<448; q+=256){
      float4 v = W4[q];
      int row = q >> 3, w4 = q & 7;
      *(float4*)&Wsl[g][row*36 + w4*4] = v;
    }
    if (t < 14) Bl[g][t] = Bs[(size_t)b*14 + t];
  }
  __syncthreads();
  // stage 1: R[c] = sum_w Wt[wtrow][w] * X[xrow][w]  (+bias for c<14)
  for (int idx=t; idx<2*NCOMP; idx+=256){
    int g = (idx >= NCOMP) ? 1 : 0;
    int c = idx - g*NCOMP;
    int b = g0+g;
    if (b < B){
      int2 ct = comp[c];
      const float* xp = &Xs[g][ct.x*36];
      const float* wp = &Wsl[g][ct.y*36];
      float acc = 0.f;
      #pragma unroll
      for (int w4=0; w4<8; w4++){
        float4 xv = *(const float4*)(xp + w4*4);
        float4 wv = *(const float4*)(wp + w4*4);
        acc += xv.x*wv.x + xv.y*wv.y + xv.z*wv.z + xv.w*wv.w;
      }
      if (c < 14) acc += Bl[g][c];
      Rs[g][c] = acc;
    }
  }
  __syncthreads();
  // stage 2: out[o] = sum CSR row
  for (int idx=t; idx<2*NCOMP; idx+=256){
    int g = (idx >= NCOMP) ? 1 : 0;
    int c = idx - g*NCOMP;
    int b = g0+g;
    if (b < B){
      int s = rst[c], L = rln[c];
      float acc = 0.f;
      for (int e=0;e<L;e++){
        int2 en = ent[s+e];
        acc += __int_as_float(en.y) * Rs[g][en.x];
      }
      out[(size_t)b*196 + c] = acc;
    }
  }
}

// ---------------- reverse-edge lookup + symmetrization ----------------
__global__ void pos_init_kernel(int* __restrict__ pos, int n){
  int t = blockIdx.x*blockDim.x + threadIdx.x;
  if (t < n) pos[t] = -1;
}
__global__ void pos_fill_kernel(int* __restrict__ pos, const int* __restrict__ ei, int E, int N){
  int t = blockIdx.x*blockDim.x + threadIdx.x;
  if (t < E) pos[ei[t]*N + ei[E+t]] = t;
}
__global__ void sym_diag_kernel(float* __restrict__ out, int N){
  int t = blockIdx.x*blockDim.x + threadIdx.x;
  if (t >= N*196) return;
  int n = t/196, rc = t - n*196, r = rc/14, c = rc - r*14;
  if (r >= c) return;
  float* M = out + (size_t)n*196;
  float a = M[r*14+c], b = M[c*14+r];
  float v = 0.5f*(a+b);
  M[r*14+c]=v; M[c*14+r]=v;
}
__global__ void sym_off_kernel(float* __restrict__ out, const int* __restrict__ ei,
                               const int* __restrict__ pos, int E, int N){
  long long t = (long long)blockIdx.x*blockDim.x + threadIdx.x;
  if (t >= (long long)E*196) return;
  int e = (int)(t/196); int rc = (int)(t - (long long)e*196);
  int r = rc/14, c = rc - r*14;
  int s = ei[e], d = ei[E+e];
  int e2 = pos[d*N+s];
  if (e2 < 0 || e2 <= e) return;
  float* Me = out + (size_t)e*196;
  float* Mf = out + (size_t)e2*196;
  float a = Me[rc], b = Mf[c*14+r];
  float v = 0.5f*(a+b);
  Me[rc]=v; Mf[c*14+r]=v;
}

static inline long long llmin(long long a, long long b){ return a<b?a:b; }
static inline long long llmax(long long a, long long b){ return a>b?a:b; }

extern "C" void kernel_launch(void* const* d_in, const int* in_sizes, int n_in,
                              void* d_out, int out_size, void* d_ws, size_t ws_size,
                              hipStream_t stream) {
  const float* fii = (const float*)d_in[0];
  const float* fij = (const float*)d_in[1];
  const float* ne  = (const float*)d_in[2];
  const int*   ei  = (const int*)d_in[3];
  const float* wii = (const float*)d_in[4];
  const float* wij = (const float*)d_in[5];
  const float* iifc_w1 = (const float*)d_in[6];
  const float* iifc_b1 = (const float*)d_in[7];
  const float* iifc_w2 = (const float*)d_in[8];
  const float* iifc_b2 = (const float*)d_in[9];
  const float* iifb_w1 = (const float*)d_in[10];
  const float* iifb_b1 = (const float*)d_in[11];
  const float* iifb_w2 = (const float*)d_in[12];
  const float* iifb_b2 = (const float*)d_in[13];
  const float* ijfc_w1 = (const float*)d_in[14];
  const float* ijfc_b1 = (const float*)d_in[15];
  const float* ijfc_w2 = (const float*)d_in[16];
  const float* ijfc_b2 = (const float*)d_in[17];
  const float* ijfb_w1 = (const float*)d_in[18];
  const float* ijfb_b1 = (const float*)d_in[19];
  const float* ijfb_w2 = (const float*)d_in[20];
  const float* ijfb_b2 = (const float*)d_in[21];
  (void)n_in; (void)out_size;
  float* out = (float*)d_out;
  const int N = in_sizes[2]/128;
  const int E = in_sizes[1]/3136;

  float* ws = (float*)d_ws;
  // static layout (floats; all offsets multiples of 4)
  size_t o_w3   = 0;                       // 1232
  size_t o_perm = o_w3 + 1232;             // 1792 (int)
  size_t o_comp = o_perm + 1792;           // 392 (int2[196])
  size_t o_rst  = o_comp + 392;            // 196
  size_t o_rln  = o_rst + 196;             // 196
  size_t o_ent  = o_rln + 196;             // 8192 (int2[4096])
  size_t o_Bp   = o_ent + 8192;            // 229376
  size_t o_bp   = o_Bp + 229376;           // 1792
  size_t o_Afc  = o_bp + 1792;
  size_t o_Bfc  = o_Afc + (size_t)N*128;
  size_t o_Afb  = o_Bfc + (size_t)N*128;
  size_t o_Bfb  = o_Afb + (size_t)N*128;
  size_t o_Wiw  = o_Bfb + (size_t)N*128;
  size_t o_Wib  = o_Wiw + (size_t)N*1792;
  size_t o_Xii  = o_Wib + (size_t)N*16;    // pad 14->16
  size_t o_pos  = o_Xii + (size_t)N*1568;
  size_t o_dyn  = o_pos + (size_t)N*N + 16;

  long long avail = (long long)(ws_size/4) - (long long)o_dyn;
  long long per_e = 128 + 16 + 1792 + 1568;   // H, Bs(pad), WtP, X
  long long CHl = avail > 0 ? avail/per_e : 2;
  CHl = llmin(CHl, E);
  CHl = llmax(CHl & ~1LL, 2);
  const int CH = (int)CHl;
  size_t o_H  = o_dyn;
  size_t o_Bs = o_H  + (size_t)CH*128;
  size_t o_Wt = o_Bs + (size_t)CH*16;
  size_t o_Xe = o_Wt + (size_t)CH*1792;

  int*  perm = (int*)(ws + o_perm);
  int2* comp = (int2*)(ws + o_comp);
  int*  rst  = (int*)(ws + o_rst);
  int*  rln  = (int*)(ws + o_rln);
  int2* ent  = (int2*)(ws + o_ent);
  int*  pos  = (int*)(ws + o_pos);

  init_kernel<<<1, 256, 0, stream>>>(ws+o_w3, perm, comp, rst, rln, ent);
  permB_kernel<<<(128*1792+255)/256, 256, 0, stream>>>(ijfc_w2, ijfc_b2, perm, ws+o_Bp, ws+o_bp);
  node_kernel<<<N, 256, 0, stream>>>(ne,
      iifc_w1, iifc_b1, iifc_w2, iifc_b2,
      iifb_w1, iifb_b1, iifb_w2, iifb_b2,
      ijfc_w1, ijfb_w1, perm,
      ws+o_Afc, ws+o_Bfc, ws+o_Afb, ws+o_Bfb, ws+o_Wiw, ws+o_Wib);
  pos_init_kernel<<<(N*N+255)/256, 256, 0, stream>>>(pos, N*N);
  pos_fill_kernel<<<(E+255)/256, 256, 0, stream>>>(pos, ei, E, N);

  // ---- diagonal ----
  {
    int gx = (N*9 + 127)/128;
    o3lin_kernel<<<dim3(gx, 9), 256, 0, stream>>>(N, fii, wii, ws+o_Xii);
    // note: diag Bs layout is N*14 packed
    expansion2_kernel<<<(N+1)/2, 256, 0, stream>>>(N, ws+o_Xii, ws+o_Wiw, ws+o_Wib,
        comp, rst, rln, ent, out);
  }

  // ---- off-diagonal, chunked ----
  for (int e0 = 0; e0 < E; e0 += CH){
    int nc = (E - e0 < CH) ? (E - e0) : CH;
    edge_hidden_kernel<<<(nc+3)/4, 256, 0, stream>>>(e0, nc, ei, E,
        ws+o_Afc, ws+o_Bfc, ws+o_Afb, ws+o_Bfb,
        ijfc_b1, ijfb_b1, ijfb_w2, ijfb_b2,
        ws+o_H, ws+o_Bs);
    wgemm2_kernel<<<dim3((nc+127)/128, 28), 256, 0, stream>>>(nc, ws+o_H, ws+o_Bp, ws+o_bp, ws+o_Wt);
    int gx = (nc*9 + 127)/128;
    o3lin_kernel<<<dim3(gx, 9), 256, 0, stream>>>(nc, fij + (size_t)e0*3136, wij, ws+o_Xe);
    expansion2_kernel<<<(nc+1)/2, 256, 0, stream>>>(nc, ws+o_Xe, ws+o_Wt, ws+o_Bs,
        comp, rst, rln, ent, out + ((size_t)N + e0)*196);
  }

  sym_diag_kernel<<<(N*196+255)/256, 256, 0, stream>>>(out, N);
  sym_off_kernel<<<(int)(((long long)E*196 + 255)/256), 256, 0, stream>>>(out + (size_t)N*196, ei, pos, E, N);
}

// Round 4
// 976.649 us; speedup vs baseline: 3.5743x; 1.2404x over previous
//
#include <hip/hip_runtime.h>
#include <math.h>

// ---------------- problem constants ----------------
#define NPATH 19
static constexpr int IRD[9]   = {1,3,3,5,5,7,7,9,9};            // 2l+1 per feat irrep
static constexpr int ICUM[9]  = {0,1,4,7,12,17,24,31,40};       // cumulative dims (sum 49)
static constexpr int P_I[NPATH]   = {0,0,0,1,1,1,1,2,2,3,3,4,4,4,4,5,5,6,8};
static constexpr int P_J[NPATH]   = {0,1,2,0,1,1,2,1,2,1,2,0,1,2,2,1,2,2,2};
static constexpr int P_K[NPATH]   = {0,1,2,1,0,2,1,1,2,2,1,2,1,0,2,2,1,2,2};
static constexpr int P_MJ[NPATH]  = {3,2,1,3,2,2,1,2,1,2,1,3,2,1,1,2,1,1,1};
static constexpr int P_MK[NPATH]  = {3,2,1,2,3,1,2,2,1,1,2,1,2,3,1,1,2,1,1};
static constexpr int P_WOFF[NPATH]= {0,288,416,448,640,832,896,960,1088,1120,1184,1248,1344,1472,1568,1600,1664,1728,1760};
static constexpr int P_W3OFF[NPATH]={0,1,10,35,44,53,98,143,170,245,320,395,420,465,490,615,720,825,1000};
// component prefix (mjk*di) and weight-row prefix (mjk)
static constexpr int CB_[NPATH] = {0,9,13,14,32,50,56,62,74,77,87,97,112,132,147,152,166,180,187}; // total 196
static constexpr int WB_[NPATH] = {0,9,13,14,20,26,28,30,34,35,37,39,42,46,49,50,52,54,55};        // total 56
#define W3J_TOT 1225
#define NCOMP 196
#define NWROW 56

__device__ __forceinline__ float silu_f(float x){ return x / (1.f + expf(-x)); }

// ---------------- Wigner-3j helpers (double, e3nn real basis) ----------------
__device__ __constant__ double FCT[16] = {1.,1.,2.,6.,24.,120.,720.,5040.,40320.,362880.,
  3628800.,39916800.,479001600.,6227020800.,87178291200.,1307674368000.};

__device__ __forceinline__ double su2_cg_d(int j1,int m1,int j2,int m2,int j3,int m3){
  int vmin = max(max(-j1+j2+m3, -j1+m1), 0);
  int vmax = min(min(j2+j3+m1, j3-j1+j2), j3+m3);
  double c = sqrt((double)(2*j3+1)*FCT[j3+j1-j2]*FCT[j3-j1+j2]*FCT[j1+j2-j3]*FCT[j3+m3]*FCT[j3-m3]
     /(FCT[j1+j2+j3+1]*FCT[j1-m1]*FCT[j1+m1]*FCT[j2-m2]*FCT[j2+m2]));
  double s = 0.0;
  for (int v=vmin; v<=vmax; v++){
    double sg = ((v+j2+m2)&1)? -1.0 : 1.0;
    s += sg*FCT[j2+j3+m1-v]*FCT[j1-m1+v]/(FCT[v]*FCT[j3-j1+j2-v]*FCT[j3+m3-v]*FCT[v+j1-j2-m3]);
  }
  return c*s;
}

__device__ double2 qval(int l, int r, int c){
  int m = r - l;
  const double r2 = 0.70710678118654752440;
  double re=0.0, im=0.0;
  if (m < 0){
    if (c == l - m) re = r2;
    else if (c == l + m) im = -r2;
  } else if (m == 0){
    if (c == l) re = 1.0;
  } else {
    double s = (m&1)? -1.0 : 1.0;
    if (c == l + m) re = s*r2;
    else if (c == l - m) im = s*r2;
  }
  switch (l & 3){
    case 0: return make_double2(re, im);
    case 1: return make_double2(im, -re);
    case 2: return make_double2(-re, -im);
    default: return make_double2(-im, re);
  }
}

__device__ __forceinline__ void dec_rc(int r, int& j, int& u, int& a){
  if (r < 3){ j=0; u=r; a=0; }
  else if (r < 9){ j=1; u=(r-3)/3; a=(r-3)%3; }
  else { j=2; u=0; a=r-9; }
}

// ---------------- w3j: one WAVE per entry, lane = one (i,k) CG term ----------------
__global__ __launch_bounds__(256) void w3j_kernel(float* __restrict__ w3){
  const int wid = threadIdx.x >> 6, lane = threadIdx.x & 63;
  const int e = blockIdx.x*4 + wid;
  if (e >= W3J_TOT) return;
  int p = 0;
  for (int q=0; q<NPATH; q++) if (e >= P_W3OFF[q]) p = q;
  const int l1 = P_J[p], l2 = P_K[p], l3 = (IRD[P_I[p]]-1)/2;
  const int n1=2*l1+1, n2=2*l2+1, n3=2*l3+1;
  const int loc = e - P_W3OFF[p];
  const int m = loc % n3; const int jl = loc / n3; const int L = jl % n2; const int j = jl / n2;
  double term = 0.0;
  if (lane < n1*n2){
    int i = lane / n2, k = lane - (lane/n2)*n2;
    double2 q1 = qval(l1,i,j);
    double2 q2 = qval(l2,k,L);
    if ((q1.x!=0.0 || q1.y!=0.0) && (q2.x!=0.0 || q2.y!=0.0)){
      int m1 = i - l1, m2 = k - l2; int m3 = m1+m2;
      if (m3 >= -l3 && m3 <= l3){
        double2 q3 = qval(l3,l3+m3,m);
        if (q3.x!=0.0 || q3.y!=0.0){
          double cg = su2_cg_d(l1,m1,l2,m2,l3,m3);
          double ar = q1.x*q2.x - q1.y*q2.y;
          double ai = q1.x*q2.y + q1.y*q2.x;
          term = (ar*q3.x + ai*q3.y) * cg;
        }
      }
    }
  }
  #pragma unroll
  for (int off=32; off>=1; off>>=1) term += __shfl_xor(term, off, 64);
  if (lane == 0) w3[e] = (float)(term / sqrt((double)n3));
}

// ---------------- tables: perm + comp + CSR (small, single block) ----------------
__global__ __launch_bounds__(256) void tables_kernel(
  const float* __restrict__ w3, int* __restrict__ perm,
  int2* __restrict__ comp, int* __restrict__ rst, int* __restrict__ rln,
  int2* __restrict__ ent)
{
  const int t = threadIdx.x;
  for (int idx = t; idx < 1792; idx += 256){
    int p = 0;
    for (int q=0; q<NPATH; q++) if (idx >= P_WOFF[q]) p = q;
    int mjk = P_MJ[p]*P_MK[p];
    int loc = idx - P_WOFF[p];
    int w = loc / mjk, uv = loc % mjk;
    perm[idx] = (WB_[p]+uv)*32 + w;
  }
  if (t < NCOMP){
    int p = 0;
    for (int q=0; q<NPATH; q++) if (t >= CB_[q]) p = q;
    int di = IRD[P_I[p]];
    int loc = t - CB_[p]; int uv = loc/di, k = loc%di;
    comp[t] = make_int2(ICUM[P_I[p]] + k, WB_[p] + uv);
  }
  __shared__ int lens[NCOMP];
  __shared__ int starts[NCOMP+1];
  if (t < NCOMP){
    int r = t/14, c = t%14;
    int j,u,a, k,v,cc;
    dec_rc(r, j,u,a); dec_rc(c, k,v,cc);
    int cnt = 0;
    for (int p=0;p<NPATH;p++){
      if (P_J[p]==j && P_K[p]==k){
        int di = IRD[P_I[p]]; int dk = 2*k+1;
        for (int kk=0; kk<di; kk++){
          float cf = w3[P_W3OFF[p] + (a*dk+cc)*di + kk];
          if (fabsf(cf) > 1e-10f) cnt++;
        }
      }
    }
    lens[t] = cnt;
  }
  __syncthreads();
  if (t == 0){
    int s = 0;
    for (int i=0;i<NCOMP;i++){ starts[i]=s; s+=lens[i]; }
    starts[NCOMP]=s;
  }
  __syncthreads();
  if (t < NCOMP){
    rst[t] = starts[t]; rln[t] = lens[t];
    int r = t/14, c = t%14;
    int j,u,a, k,v,cc;
    dec_rc(r, j,u,a); dec_rc(c, k,v,cc);
    int pp = starts[t];
    for (int p=0;p<NPATH;p++){
      if (P_J[p]==j && P_K[p]==k){
        int di = IRD[P_I[p]]; int dk = 2*k+1; int mk = P_MK[p];
        for (int kk=0; kk<di; kk++){
          float cf = w3[P_W3OFF[p] + (a*dk+cc)*di + kk];
          if (fabsf(cf) > 1e-10f){
            int ridx = CB_[p] + (u*mk+v)*di + kk;
            ent[pp++] = make_int2(ridx, __float_as_int(cf * (1.f/32.f)));
          }
        }
      }
    }
  }
}

// ---------------- permute B columns of the big weight GEMM ----------------
__global__ void permB_kernel(const float* __restrict__ W2, const float* __restrict__ b2,
                             const int* __restrict__ perm,
                             float* __restrict__ Bp, float* __restrict__ bp){
  int idx = blockIdx.x*256 + threadIdx.x;
  if (idx < 128*1792){
    int o = idx % 1792; int k = idx / 1792;
    Bp[(size_t)k*1792 + perm[o]] = W2[idx];
  }
  if (idx < 1792) bp[perm[idx]] = b2[idx];
}

// ---------------- node precompute ----------------
__global__ __launch_bounds__(256) void node_kernel(
  const float* __restrict__ ne,
  const float* __restrict__ W1ii, const float* __restrict__ b1ii,
  const float* __restrict__ W2ii, const float* __restrict__ b2ii,
  const float* __restrict__ W1bii, const float* __restrict__ b1bii,
  const float* __restrict__ W2bii, const float* __restrict__ b2bii,
  const float* __restrict__ W1ij, const float* __restrict__ W1bij,
  const int* __restrict__ perm,
  float* __restrict__ Afc, float* __restrict__ Bfc,
  float* __restrict__ Afb, float* __restrict__ Bfb,
  float* __restrict__ Wiw, float* __restrict__ Wib)
{
  int n = blockIdx.x, t = threadIdx.x;
  __shared__ float nel[128], hii[128], hbi[128];
  if (t < 128) nel[t] = ne[(size_t)n*128 + t];
  __syncthreads();
  int c = t & 127;
  bool hi = t >= 128;
  {
    const float* Wm = hi ? W1bii : W1ii;
    float a = hi ? b1bii[c] : b1ii[c];
    for (int j=0;j<128;j++) a += nel[j]*Wm[j*128+c];
    float sv = silu_f(a);
    if (hi) hbi[c]=sv; else hii[c]=sv;
  }
  {
    const float* base = W1ij + (hi ? 128*128 : 0);
    float a=0.f; for (int j=0;j<128;j++) a += nel[j]*base[j*128+c];
    (hi?Bfc:Afc)[(size_t)n*128+c] = a;
  }
  {
    const float* base = W1bij + (hi ? 128*128 : 0);
    float a=0.f; for (int j=0;j<128;j++) a += nel[j]*base[j*128+c];
    (hi?Bfb:Afb)[(size_t)n*128+c] = a;
  }
  __syncthreads();
  for (int o=t; o<1792; o+=256){
    float a = b2ii[o];
    for (int cc=0;cc<128;cc++) a += hii[cc]*W2ii[cc*1792+o];
    Wiw[(size_t)n*1792 + perm[o]] = a;   // permuted layout
  }
  if (t < 14){
    float a = b2bii[t];
    for (int cc=0;cc<128;cc++) a += hbi[cc]*W2bii[cc*14+t];
    Wib[(size_t)n*14+t]=a;
  }
}

// ---------------- per-edge hidden: H[nc,128], Bs[nc,14] ----------------
__global__ __launch_bounds__(256) void edge_hidden_kernel(
  int e0, int nc, const int* __restrict__ ei, int E,
  const float* __restrict__ Afc, const float* __restrict__ Bfc,
  const float* __restrict__ Afb, const float* __restrict__ Bfb,
  const float* __restrict__ b1fc, const float* __restrict__ b1fb,
  const float* __restrict__ W2b, const float* __restrict__ b2b,
  float* __restrict__ H, float* __restrict__ Bs)
{
  int wid = threadIdx.x >> 6, lane = threadIdx.x & 63;
  int el = blockIdx.x*4 + wid;
  if (el >= nc) return;
  int e = e0 + el;
  int s = ei[e], d = ei[E+e];
  const float* As_ = Afc + (size_t)s*128; const float* Bd = Bfc + (size_t)d*128;
  float x0 = As_[lane]+Bd[lane]+b1fc[lane];
  float x1 = As_[lane+64]+Bd[lane+64]+b1fc[lane+64];
  H[(size_t)el*128+lane]    = silu_f(x0);
  H[(size_t)el*128+lane+64] = silu_f(x1);
  const float* Ab = Afb + (size_t)s*128; const float* Bb = Bfb + (size_t)d*128;
  float y0 = Ab[lane]+Bb[lane]+b1fb[lane];
  float y1 = Ab[lane+64]+Bb[lane+64]+b1fb[lane+64];
  float g0 = silu_f(y0), g1 = silu_f(y1);
  float acc[14];
  #pragma unroll
  for (int k=0;k<14;k++) acc[k] = g0*W2b[lane*14+k] + g1*W2b[(lane+64)*14+k];
  #pragma unroll
  for (int k=0;k<14;k++){
    for (int off=32; off>=1; off>>=1) acc[k] += __shfl_xor(acc[k], off, 64);
  }
  if (lane == 0){
    #pragma unroll
    for (int k=0;k<14;k++) Bs[(size_t)el*14+k] = acc[k] + b2b[k];
  }
}

// ---------------- weights GEMM v3: C[M,1792] = A[M,128]@Bp + bp ----------------
// tile 128x128, BK=32, thread 8x8; A transposed in LDS so inner loop is b128-only.
__global__ __launch_bounds__(256) void wgemm2_kernel(
  int M, const float* __restrict__ A, const float* __restrict__ Bp,
  const float* __restrict__ bp, float* __restrict__ C)
{
  __shared__ __align__(16) float As2[32][132];  // [k][row], padded
  __shared__ __align__(16) float Bsh[32][132];  // [k][col], padded
  const int t = threadIdx.x;
  const int m0 = blockIdx.x*128, n0 = blockIdx.y*128;
  const int ty = t >> 4, tx = t & 15;           // rows ty*8.., cols tx*8..
  float acc[8][8] = {};
  for (int kp=0; kp<4; kp++){
    __syncthreads();
    // stage A transposed: 128 rows x 32 k = 1024 float4
    for (int q=t; q<1024; q+=256){
      int row = q >> 3, k4 = q & 7;
      float4 v = make_float4(0.f,0.f,0.f,0.f);
      if (m0+row < M) v = *(const float4*)&A[(size_t)(m0+row)*128 + kp*32 + k4*4];
      As2[k4*4+0][row] = v.x; As2[k4*4+1][row] = v.y;
      As2[k4*4+2][row] = v.z; As2[k4*4+3][row] = v.w;
    }
    // stage B: 32 k x 128 cols = 1024 float4
    for (int q=t; q<1024; q+=256){
      int k = q >> 5, c4 = q & 31;
      *(float4*)&Bsh[k][c4*4] = *(const float4*)&Bp[(size_t)(kp*32+k)*1792 + n0 + c4*4];
    }
    __syncthreads();
    #pragma unroll 4
    for (int k=0;k<32;k++){
      float4 a0 = *(const float4*)&As2[k][ty*8];
      float4 a1 = *(const float4*)&As2[k][ty*8+4];
      float4 b0 = *(const float4*)&Bsh[k][tx*8];
      float4 b1 = *(const float4*)&Bsh[k][tx*8+4];
      float av[8]={a0.x,a0.y,a0.z,a0.w,a1.x,a1.y,a1.z,a1.w};
      float bv[8]={b0.x,b0.y,b0.z,b0.w,b1.x,b1.y,b1.z,b1.w};
      #pragma unroll
      for (int i=0;i<8;i++){
        #pragma unroll
        for (int jj=0;jj<8;jj++) acc[i][jj] += av[i]*bv[jj];
      }
    }
  }
  float4 bb0 = *(const float4*)&bp[n0 + tx*8];
  float4 bb1 = *(const float4*)&bp[n0 + tx*8 + 4];
  #pragma unroll
  for (int i=0;i<8;i++){
    int row = m0 + ty*8 + i;
    if (row < M){
      float4 o0, o1;
      o0.x = acc[i][0]+bb0.x; o0.y = acc[i][1]+bb0.y; o0.z = acc[i][2]+bb0.z; o0.w = acc[i][3]+bb0.w;
      o1.x = acc[i][4]+bb1.x; o1.y = acc[i][5]+bb1.y; o1.z = acc[i][6]+bb1.z; o1.w = acc[i][7]+bb1.w;
      *(float4*)&C[(size_t)row*1792 + n0 + tx*8]     = o0;
      *(float4*)&C[(size_t)row*1792 + n0 + tx*8 + 4] = o1;
    }
  }
}

// ---------------- o3_linear GEMM: X[item][49][32] ----------------
__global__ __launch_bounds__(256) void o3lin_kernel(
  int B, const float* __restrict__ F, const float* __restrict__ W, float* __restrict__ X)
{
  const int ir = blockIdx.y;
  const int di = IRD[ir], cum = ICUM[ir];
  const int M = B*di;
  const int r0 = blockIdx.x*128;
  if (r0 >= M) return;
  __shared__ __align__(16) float As2[64][128];  // [u][row]
  __shared__ __align__(16) float Wsh[64*32];    // [u][o]
  const int t = threadIdx.x;
  for (int q=t; q<512; q+=256)
    *(float4*)&Wsh[q*4] = *(const float4*)&W[ir*2048 + q*4];
  {
    int r = t & 127, uh = t >> 7;          // uh in {0,1}
    int row = r0 + r;
    if (row < M){
      int e = row / di, m = row - e*di;
      const float* fb = F + (size_t)e*3136 + cum*64 + m;
      #pragma unroll 8
      for (int i=0;i<32;i++){
        int u = uh*32 + i;
        As2[u][r] = fb[u*di];
      }
    } else {
      #pragma unroll 8
      for (int i=0;i<32;i++) As2[uh*32+i][r] = 0.f;
    }
  }
  __syncthreads();
  const int ty = t >> 3, tx = t & 7;       // rows ty*4.., cols tx*4..
  float acc[4][4] = {};
  #pragma unroll 4
  for (int u=0;u<64;u++){
    float4 a = *(const float4*)&As2[u][ty*4];
    float4 b = *(const float4*)&Wsh[u*32 + tx*4];
    acc[0][0]+=a.x*b.x; acc[0][1]+=a.x*b.y; acc[0][2]+=a.x*b.z; acc[0][3]+=a.x*b.w;
    acc[1][0]+=a.y*b.x; acc[1][1]+=a.y*b.y; acc[1][2]+=a.y*b.z; acc[1][3]+=a.y*b.w;
    acc[2][0]+=a.z*b.x; acc[2][1]+=a.z*b.y; acc[2][2]+=a.z*b.z; acc[2][3]+=a.z*b.w;
    acc[3][0]+=a.w*b.x; acc[3][1]+=a.w*b.y; acc[3][2]+=a.w*b.z; acc[3][3]+=a.w*b.w;
  }
  #pragma unroll
  for (int i=0;i<4;i++){
    int row = r0 + ty*4 + i;
    if (row < M){
      int e = row / di, m = row - e*di;
      float4 o;
      o.x = acc[i][0]*0.125f; o.y = acc[i][1]*0.125f;
      o.z = acc[i][2]*0.125f; o.w = acc[i][3]*0.125f;
      *(float4*)&X[(size_t)e*1568 + (cum+m)*32 + tx*4] = o;
    }
  }
}

// ---------------- expansion v2: R components + CSR apply ----------------
__global__ __launch_bounds__(256) void expansion2_kernel(
  int B, const float* __restrict__ X, const float* __restrict__ Wt,
  const float* __restrict__ Bs,
  const int2* __restrict__ comp, const int* __restrict__ rst,
  const int* __restrict__ rln, const int2* __restrict__ ent,
  float* __restrict__ out)
{
  __shared__ __align__(16) float Xs[2][49*36];
  __shared__ __align__(16) float Wsl[2][56*36];
  __shared__ float Rs[2][200];
  __shared__ float Bl[2][14];
  const int t = threadIdx.x;
  const int g0 = blockIdx.x*2;
  for (int g=0; g<2; g++){
    int b = g0+g;
    if (b >= B) break;
    const float4* X4 = (const float4*)(X + (size_t)b*1568);
    for (int q=t; q<392; q+=256){
      float4 v = X4[q];
      int row = q >> 3, w4 = q & 7;
      *(float4*)&Xs[g][row*36 + w4*4] = v;
    }
    const float4* W4 = (const float4*)(Wt + (size_t)b*1792);
    for (int q=t; q<448; q+=256){
      float4 v = W4[q];
      int row = q >> 3, w4 = q & 7;
      *(float4*)&Wsl[g][row*36 + w4*4] = v;
    }
    if (t < 14) Bl[g][t] = Bs[(size_t)b*14 + t];
  }
  __syncthreads();
  for (int idx=t; idx<2*NCOMP; idx+=256){
    int g = (idx >= NCOMP) ? 1 : 0;
    int c = idx - g*NCOMP;
    int b = g0+g;
    if (b < B){
      int2 ct = comp[c];
      const float* xp = &Xs[g][ct.x*36];
      const float* wp = &Wsl[g][ct.y*36];
      float acc = 0.f;
      #pragma unroll
      for (int w4=0; w4<8; w4++){
        float4 xv = *(const float4*)(xp + w4*4);
        float4 wv = *(const float4*)(wp + w4*4);
        acc += xv.x*wv.x + xv.y*wv.y + xv.z*wv.z + xv.w*wv.w;
      }
      if (c < 14) acc += Bl[g][c];
      Rs[g][c] = acc;
    }
  }
  __syncthreads();
  for (int idx=t; idx<2*NCOMP; idx+=256){
    int g = (idx >= NCOMP) ? 1 : 0;
    int c = idx - g*NCOMP;
    int b = g0+g;
    if (b < B){
      int s = rst[c], L = rln[c];
      float acc = 0.f;
      for (int e=0;e<L;e++){
        int2 en = ent[s+e];
        acc += __int_as_float(en.y) * Rs[g][en.x];
      }
      out[(size_t)b*196 + c] = acc;
    }
  }
}

// ---------------- reverse-edge lookup + symmetrization ----------------
__global__ void pos_init_kernel(int* __restrict__ pos, int n){
  int t = blockIdx.x*blockDim.x + threadIdx.x;
  if (t < n) pos[t] = -1;
}
__global__ void pos_fill_kernel(int* __restrict__ pos, const int* __restrict__ ei, int E, int N){
  int t = blockIdx.x*blockDim.x + threadIdx.x;
  if (t < E) pos[ei[t]*N + ei[E+t]] = t;
}
__global__ void sym_diag_kernel(float* __restrict__ out, int N){
  int t = blockIdx.x*blockDim.x + threadIdx.x;
  if (t >= N*196) return;
  int n = t/196, rc = t - n*196, r = rc/14, c = rc - r*14;
  if (r >= c) return;
  float* M = out + (size_t)n*196;
  float a = M[r*14+c], b = M[c*14+r];
  float v = 0.5f*(a+b);
  M[r*14+c]=v; M[c*14+r]=v;
}
__global__ void sym_off_kernel(float* __restrict__ out, const int* __restrict__ ei,
                               const int* __restrict__ pos, int E, int N){
  long long t = (long long)blockIdx.x*blockDim.x + threadIdx.x;
  if (t >= (long long)E*196) return;
  int e = (int)(t/196); int rc = (int)(t - (long long)e*196);
  int r = rc/14, c = rc - r*14;
  int s = ei[e], d = ei[E+e];
  int e2 = pos[d*N+s];
  if (e2 < 0 || e2 <= e) return;
  float* Me = out + (size_t)e*196;
  float* Mf = out + (size_t)e2*196;
  float a = Me[rc], b = Mf[c*14+r];
  float v = 0.5f*(a+b);
  Me[rc]=v; Mf[c*14+r]=v;
}

static inline long long llmin(long long a, long long b){ return a<b?a:b; }
static inline long long llmax(long long a, long long b){ return a>b?a:b; }

extern "C" void kernel_launch(void* const* d_in, const int* in_sizes, int n_in,
                              void* d_out, int out_size, void* d_ws, size_t ws_size,
                              hipStream_t stream) {
  const float* fii = (const float*)d_in[0];
  const float* fij = (const float*)d_in[1];
  const float* ne  = (const float*)d_in[2];
  const int*   ei  = (const int*)d_in[3];
  const float* wii = (const float*)d_in[4];
  const float* wij = (const float*)d_in[5];
  const float* iifc_w1 = (const float*)d_in[6];
  const float* iifc_b1 = (const float*)d_in[7];
  const float* iifc_w2 = (const float*)d_in[8];
  const float* iifc_b2 = (const float*)d_in[9];
  const float* iifb_w1 = (const float*)d_in[10];
  const float* iifb_b1 = (const float*)d_in[11];
  const float* iifb_w2 = (const float*)d_in[12];
  const float* iifb_b2 = (const float*)d_in[13];
  const float* ijfc_w1 = (const float*)d_in[14];
  const float* ijfc_b1 = (const float*)d_in[15];
  const float* ijfc_w2 = (const float*)d_in[16];
  const float* ijfc_b2 = (const float*)d_in[17];
  const float* ijfb_w1 = (const float*)d_in[18];
  const float* ijfb_b1 = (const float*)d_in[19];
  const float* ijfb_w2 = (const float*)d_in[20];
  const float* ijfb_b2 = (const float*)d_in[21];
  (void)n_in; (void)out_size;
  float* out = (float*)d_out;
  const int N = in_sizes[2]/128;
  const int E = in_sizes[1]/3136;

  float* ws = (float*)d_ws;
  size_t o_w3   = 0;                       // 1232
  size_t o_perm = o_w3 + 1232;             // 1792 (int)
  size_t o_comp = o_perm + 1792;           // 392 (int2[196])
  size_t o_rst  = o_comp + 392;            // 196
  size_t o_rln  = o_rst + 196;             // 196
  size_t o_ent  = o_rln + 196;             // 8192 (int2[4096])
  size_t o_Bp   = o_ent + 8192;            // 229376
  size_t o_bp   = o_Bp + 229376;           // 1792
  size_t o_Afc  = o_bp + 1792;
  size_t o_Bfc  = o_Afc + (size_t)N*128;
  size_t o_Afb  = o_Bfc + (size_t)N*128;
  size_t o_Bfb  = o_Afb + (size_t)N*128;
  size_t o_Wiw  = o_Bfb + (size_t)N*128;
  size_t o_Wib  = o_Wiw + (size_t)N*1792;
  size_t o_Xii  = o_Wib + (size_t)N*16;    // pad 14->16
  size_t o_pos  = o_Xii + (size_t)N*1568;
  size_t o_dyn  = o_pos + (size_t)N*N + 16;

  long long avail = (long long)(ws_size/4) - (long long)o_dyn;
  long long per_e = 128 + 16 + 1792 + 1568;   // H, Bs(pad), WtP, X
  long long CHl = avail > 0 ? avail/per_e : 2;
  CHl = llmin(CHl, E);
  CHl = llmax(CHl & ~1LL, 2);
  const int CH = (int)CHl;
  size_t o_H  = o_dyn;
  size_t o_Bs = o_H  + (size_t)CH*128;
  size_t o_Wt = o_Bs + (size_t)CH*16;
  size_t o_Xe = o_Wt + (size_t)CH*1792;

  int*  perm = (int*)(ws + o_perm);
  int2* comp = (int2*)(ws + o_comp);
  int*  rst  = (int*)(ws + o_rst);
  int*  rln  = (int*)(ws + o_rln);
  int2* ent  = (int2*)(ws + o_ent);
  int*  pos  = (int*)(ws + o_pos);

  w3j_kernel<<<(W3J_TOT+3)/4, 256, 0, stream>>>(ws + o_w3);
  tables_kernel<<<1, 256, 0, stream>>>(ws+o_w3, perm, comp, rst, rln, ent);
  permB_kernel<<<(128*1792+255)/256, 256, 0, stream>>>(ijfc_w2, ijfc_b2, perm, ws+o_Bp, ws+o_bp);
  node_kernel<<<N, 256, 0, stream>>>(ne,
      iifc_w1, iifc_b1, iifc_w2, iifc_b2,
      iifb_w1, iifb_b1, iifb_w2, iifb_b2,
      ijfc_w1, ijfb_w1, perm,
      ws+o_Afc, ws+o_Bfc, ws+o_Afb, ws+o_Bfb, ws+o_Wiw, ws+o_Wib);
  pos_init_kernel<<<(N*N+255)/256, 256, 0, stream>>>(pos, N*N);
  pos_fill_kernel<<<(E+255)/256, 256, 0, stream>>>(pos, ei, E, N);

  // ---- diagonal ----
  {
    int gx = (N*9 + 127)/128;
    o3lin_kernel<<<dim3(gx, 9), 256, 0, stream>>>(N, fii, wii, ws+o_Xii);
    expansion2_kernel<<<(N+1)/2, 256, 0, stream>>>(N, ws+o_Xii, ws+o_Wiw, ws+o_Wib,
        comp, rst, rln, ent, out);
  }

  // ---- off-diagonal, chunked ----
  for (int e0 = 0; e0 < E; e0 += CH){
    int nc = (E - e0 < CH) ? (E - e0) : CH;
    edge_hidden_kernel<<<(nc+3)/4, 256, 0, stream>>>(e0, nc, ei, E,
        ws+o_Afc, ws+o_Bfc, ws+o_Afb, ws+o_Bfb,
        ijfc_b1, ijfb_b1, ijfb_w2, ijfb_b2,
        ws+o_H, ws+o_Bs);
    wgemm2_kernel<<<dim3((nc+127)/128, 14), 256, 0, stream>>>(nc, ws+o_H, ws+o_Bp, ws+o_bp, ws+o_Wt);
    int gx = (nc*9 + 127)/128;
    o3lin_kernel<<<dim3(gx, 9), 256, 0, stream>>>(nc, fij + (size_t)e0*3136, wij, ws+o_Xe);
    expansion2_kernel<<<(nc+1)/2, 256, 0, stream>>>(nc, ws+o_Xe, ws+o_Wt, ws+o_Bs,
        comp, rst, rln, ent, out + ((size_t)N + e0)*196);
  }

  sym_diag_kernel<<<(N*196+255)/256, 256, 0, stream>>>(out, N);
  sym_off_kernel<<<(int)(((long long)E*196 + 255)/256), 256, 0, stream>>>(out + (size_t)N*196, ei, pos, E, N);
}